// Round 7
// baseline (11760.259 us; speedup 1.0000x reference)
//
#include <hip/hip_runtime.h>

typedef unsigned short u16;
typedef unsigned int   u32;
typedef unsigned long long u64;

#define LTC_B 32
#define LTC_L 1024
#define LTC_D 512
#define LTC_H 512
#define NG 8               // groups
#define NP 16              // producer WGs per group (each owns 32+32 W rows)
#define NBG 4              // batches per group

typedef _Float16 f16x8  __attribute__((ext_vector_type(8)));
typedef _Float16 f16x2t __attribute__((ext_vector_type(2)));
typedef float    f32x4  __attribute__((ext_vector_type(4)));

static __device__ __forceinline__ u32 packh(float a, float b) {
    f16x2t p; p[0] = (_Float16)a; p[1] = (_Float16)b;
    return __builtin_bit_cast(u32, p);
}
static __device__ __forceinline__ float unplo(u32 w) {
    return (float)__builtin_bit_cast(f16x2t, w)[0];
}
static __device__ __forceinline__ float unphi(u32 w) {
    return (float)__builtin_bit_cast(f16x2t, w)[1];
}
static __device__ __forceinline__ float sigm(float x) {
    return 1.f / (1.f + __expf(-x));
}
static __device__ __forceinline__ float tanh_f(float x) {
    float e = __expf(2.f * x);          // inf-safe: e=inf -> 1, e=0 -> -1
    return 1.f - 2.f / (e + 1.f);
}
static __device__ __forceinline__ f16x8 cvt8(const float* p) {
    const float4 a = *(const float4*)p;
    const float4 b = *(const float4*)(p + 4);
    f16x8 r;
    r[0] = (_Float16)a.x; r[1] = (_Float16)a.y; r[2] = (_Float16)a.z; r[3] = (_Float16)a.w;
    r[4] = (_Float16)b.x; r[5] = (_Float16)b.y; r[6] = (_Float16)b.z; r[7] = (_Float16)b.w;
    return r;
}
static __device__ __forceinline__ bool stamp2(u64 a, u64 b, u32 k) {
    return ((u32)(a >> 32) == k) & ((u32)(b >> 32) == k);
}

// ---------------------------------------------------------------------------
// C[M,512](f16) = A[M,512](f32) . W[:,:512]^T(f32, row stride ldb) + bias(f32)
// ---------------------------------------------------------------------------
__global__ __launch_bounds__(256) void gemm_a32_c16(
    const float* __restrict__ A, const float* __restrict__ W, int ldb,
    const float* __restrict__ bias, u16* __restrict__ C)
{
    const int wave = threadIdx.x >> 6;
    const int lane = threadIdx.x & 63;
    const int tile = blockIdx.x * 4 + wave;
    const int nt = tile & 7;
    const int mt = tile >> 3;
    const int r16 = lane & 15;
    const int kq  = (lane >> 4) * 8;

    const float* ap = A + (size_t)(mt * 64 + r16) * LTC_D + kq;
    const float* wp = W + (size_t)(nt * 64 + r16) * ldb + kq;

    f32x4 acc[4][4];
    #pragma unroll
    for (int i = 0; i < 4; ++i)
        #pragma unroll
        for (int jj = 0; jj < 4; ++jj) acc[i][jj] = (f32x4){0.f, 0.f, 0.f, 0.f};

    for (int ks = 0; ks < 16; ++ks) {
        f16x8 af[4], bf[4];
        #pragma unroll
        for (int t = 0; t < 4; ++t) {
            af[t] = cvt8(ap + (size_t)t * 16 * LTC_D + ks * 32);
            bf[t] = cvt8(wp + (size_t)t * 16 * ldb  + ks * 32);
        }
        #pragma unroll
        for (int mi = 0; mi < 4; ++mi)
            #pragma unroll
            for (int ni = 0; ni < 4; ++ni)
                acc[mi][ni] = __builtin_amdgcn_mfma_f32_16x16x32_f16(
                    af[mi], bf[ni], acc[mi][ni], 0, 0, 0);
    }
    const int row = (lane >> 4) * 4;   // C/D: col=lane&15 (n), row=(lane>>4)*4+reg (m)
    const int col = lane & 15;
    #pragma unroll
    for (int ni = 0; ni < 4; ++ni) {
        const int n = nt * 64 + ni * 16 + col;
        const float bv = bias[n];
        #pragma unroll
        for (int mi = 0; mi < 4; ++mi)
            #pragma unroll
            for (int r = 0; r < 4; ++r) {
                _Float16 h = (_Float16)(acc[mi][ni][r] + bv);
                C[(size_t)(mt * 64 + mi * 16 + row + r) * LTC_H + n] =
                    __builtin_bit_cast(u16, h);
            }
    }
}

// ---------------------------------------------------------------------------
// C[M,512](f32) = A[M,512](f16) . W^T(f32, row stride 512) + bias(f32)
// ---------------------------------------------------------------------------
__global__ __launch_bounds__(256) void gemm_a16_c32(
    const u16* __restrict__ A, const float* __restrict__ W,
    const float* __restrict__ bias, float* __restrict__ C)
{
    const int wave = threadIdx.x >> 6;
    const int lane = threadIdx.x & 63;
    const int tile = blockIdx.x * 4 + wave;
    const int nt = tile & 7;
    const int mt = tile >> 3;
    const int r16 = lane & 15;
    const int kq  = (lane >> 4) * 8;

    const _Float16* ap = (const _Float16*)A + (size_t)(mt * 64 + r16) * LTC_D + kq;
    const float*    wp = W + (size_t)(nt * 64 + r16) * LTC_H + kq;

    f32x4 acc[4][4];
    #pragma unroll
    for (int i = 0; i < 4; ++i)
        #pragma unroll
        for (int jj = 0; jj < 4; ++jj) acc[i][jj] = (f32x4){0.f, 0.f, 0.f, 0.f};

    for (int ks = 0; ks < 16; ++ks) {
        f16x8 af[4], bf[4];
        #pragma unroll
        for (int t = 0; t < 4; ++t) {
            af[t] = *(const f16x8*)(ap + (size_t)t * 16 * LTC_D + ks * 32);
            bf[t] = cvt8(wp + (size_t)t * 16 * LTC_H + ks * 32);
        }
        #pragma unroll
        for (int mi = 0; mi < 4; ++mi)
            #pragma unroll
            for (int ni = 0; ni < 4; ++ni)
                acc[mi][ni] = __builtin_amdgcn_mfma_f32_16x16x32_f16(
                    af[mi], bf[ni], acc[mi][ni], 0, 0, 0);
    }
    const int row = (lane >> 4) * 4;
    const int col = lane & 15;
    #pragma unroll
    for (int ni = 0; ni < 4; ++ni) {
        const int n = nt * 64 + ni * 16 + col;
        const float bv = bias[n];
        #pragma unroll
        for (int mi = 0; mi < 4; ++mi)
            #pragma unroll
            for (int r = 0; r < 4; ++r)
                C[(size_t)(mt * 64 + mi * 16 + row + r) * LTC_H + n] =
                    acc[mi][ni][r] + bv;
    }
}

// ---------------------------------------------------------------------------
// ODE scan: 8 groups x 4 batches, 16 producer WGs per group (128 WGs).
// Round-6 batch-stream pipeline (verified, 9.9ms) + A-OPERAND BROADCAST:
// the MFMA A-fragment reads hTu[lane&3] instead of hTu[lane&15], so lanes
// 4-15 load COPIES of batch rows 0-3 instead of never-written zero rows.
// Per ds_read_b128 the wave now touches only 16 distinct LDS addresses
// (4-lane same-address groups -> HW broadcast, conflict-free, ~4x less
// LDS occupancy). MFMA output rows 4-15 become duplicates of rows 0-3 and
// land in red2 entries that are never read (updates consume m=ub in 0..3
// only) -> consumed results bit-identical. Race confinement unchanged:
// garbage from concurrently-written hTu rows flows only to unread red2
// rows (phase A writes rows 2-3 / update_X consumes m 0-1; phase B-C
// writes rows 0-1 / update_Y consumes m 2-3). hTu shrinks to 4 rows;
// red2 stride 17->19 (breaks 4-way write-conflict chains, max 2-way).
// Pipeline phases (all loads issued AND consumed within one barrier
// interval — round-5 lesson: __syncthreads drains vmcnt(0)):
//   phase A: issue gather_Y[k] | matvec_X -> red2[0] | check Y -> hTu 2-3
//   phase B: update_X + publish X[k+1] | matvec_Y -> red2[1]
//   phase C: issue gather_X[k+1] | update_Y + publish Y[k+1] | check X
// Exchange channel = the VALIDATED one, bytes unchanged: stamped u64,
// relaxed agent-scope atomics, bounded spin budget (protocol failure =>
// wrong answer via absmax, never a hang). Parity safety by the transitive
// stamp argument (publishing t+2 requires all WGs checked t+1, hence all
// finished reading t).
// ---------------------------------------------------------------------------
__global__ __launch_bounds__(256) void ltc_scan(
    u32* __restrict__ drive,            // f16 pairs; rewritten with fwd
    const u32* __restrict__ gatex,      // f16 pairs
    const float* __restrict__ W_rec,
    const float* __restrict__ W_gate,
    const float* __restrict__ log_tau,
    u64* __restrict__ hbuf,             // [2 par][8 g][4 b][256] stamped pairs
    float* __restrict__ hlast)
{
    const int g   = blockIdx.x & 7;     // group
    const int p   = blockIdx.x >> 3;    // producer slice 0..15
    const int tid = threadIdx.x;
    const int lane = tid & 63;
    const int wv   = tid >> 6;          // n-tile: 0-1 rec rows, 2-3 gate rows

    __shared__ u32 hTu[4][260];         // h pairs; rows 0-1 = X, 2-3 = Y
    __shared__ float red2[2][64][19];   // [0]=X matvec results, [1]=Y

    // ---- one-time: B-fragments (my 32 W_rec + 32 Wg_h rows) into registers
    const int nl = wv * 16 + (lane & 15);      // 0..63
    const int kq = (lane >> 4) * 8;
    const float* wrow = (nl < 32)
        ? (W_rec  + (size_t)(32 * p + nl) * LTC_H)
        : (W_gate + (size_t)(32 * p + nl - 32) * (LTC_D + LTC_H) + LTC_D);
    f16x8 Wf[16];
    #pragma unroll
    for (int ks = 0; ks < 16; ++ks) Wf[ks] = cvt8(wrow + ks * 32 + kq);

    for (int i = tid; i < 4 * 260; i += 256) (&hTu[0][0])[i] = 0;  // h0 = 0

    // ---- update-thread setup (tid<64: 4 b x 16 pairs; tid<32 = stream X)
    const int ub = tid >> 4;            // local batch (tid<64)
    const int jp = tid & 15;
    const int j0 = 32 * p + 2 * jp;
    const int gb = g * NBG + ub;        // global batch
    float h0 = 0.f, h1 = 0.f, stau0 = 0.f, stau1 = 0.f;
    size_t dwofs = 0;
    if (tid < 64) {
        stau0 = (1.f / 6.f) * __expf(-log_tau[j0]);
        stau1 = (1.f / 6.f) * __expf(-log_tau[j0 + 1]);
        dwofs = (size_t)gb * LTC_L * 256 + 16 * p + jp;
        // prologue: publish initial h=0 with stamp 0 into parity 0
        __hip_atomic_store(hbuf + (size_t)g * (NBG * 256) + (size_t)ub * 256
                               + 16 * p + jp,
                           0ull, __ATOMIC_RELAXED, __HIP_MEMORY_SCOPE_AGENT);
    }
    __syncthreads();

    // A-operand broadcast: 4 lanes per 16-lane quad share each address
    const _Float16* hrow = (const _Float16*)&hTu[lane & 3][0];
    const int redn = wv * 16 + (lane & 15);
    const int redb = (lane >> 4) * 4;
    u32 kp1 = 0;                        // stamp of current (gathered) state
    int budget = 1 << 22;               // global failing-poll budget (no hangs)
    const bool own = ((tid >> 4) == p); // my polled column is published by MY WG

    // prime l=0 inputs
    u32 dw = 0, gw = 0;
    if (tid < 64) { dw = drive[dwofs]; gw = gatex[dwofs]; }

    for (int l = 0; l < LTC_L; ++l) {
        const float d0 = unplo(dw), d1 = unphi(dw);
        const float gx0 = unplo(gw), gx1 = unphi(gw);
        // prefetch next step's inputs (drains at next phase-A barrier)
        u32 dn = 0, gn = 0;
        if (tid < 64 && l + 1 < LTC_L) {
            dn = drive[dwofs + (size_t)(l + 1) * 256];
            gn = gatex[dwofs + (size_t)(l + 1) * 256];
        }
        #pragma unroll 1
        for (int s = 0; s < 6; ++s) {
            const u32 kold = kp1, knew = kp1 + 1;
            const size_t pbOld = (size_t)((kold & 1u) * NG + g) * (NBG * 256);
            const size_t pbNew = (size_t)((knew & 1u) * NG + g) * (NBG * 256);
            const u64* sbO = hbuf + pbOld + tid;
            const u64* sbN = hbuf + pbNew + tid;

            // ============ phase A ============
            u64 y0 = 0, y1 = 0;
            if (!own) {                 // issue gather_Y[kold] (old -> hits)
                y0 = __hip_atomic_load(sbO + 512, __ATOMIC_RELAXED,
                                       __HIP_MEMORY_SCOPE_AGENT);
                y1 = __hip_atomic_load(sbO + 768, __ATOMIC_RELAXED,
                                       __HIP_MEMORY_SCOPE_AGENT);
            }
            {   // matvec_X -> red2[0] (RTT of gather_Y hides under this)
                f32x4 acc0 = (f32x4){0.f, 0.f, 0.f, 0.f}, acc1 = acc0;
                #pragma unroll
                for (int ks = 0; ks < 16; ks += 2) {
                    const f16x8 a0 = *(const f16x8*)(hrow + ks * 32 + kq);
                    const f16x8 a1 = *(const f16x8*)(hrow + (ks + 1) * 32 + kq);
                    acc0 = __builtin_amdgcn_mfma_f32_16x16x32_f16(a0, Wf[ks],     acc0, 0, 0, 0);
                    acc1 = __builtin_amdgcn_mfma_f32_16x16x32_f16(a1, Wf[ks + 1], acc1, 0, 0, 0);
                }
                #pragma unroll
                for (int r = 0; r < 4; ++r) red2[0][redn][redb + r] = acc0[r] + acc1[r];
            }
            if (!own) {
                while (!stamp2(y0, y1, kold) && --budget > 0) {
                    y0 = __hip_atomic_load(sbO + 512, __ATOMIC_RELAXED,
                                           __HIP_MEMORY_SCOPE_AGENT);
                    y1 = __hip_atomic_load(sbO + 768, __ATOMIC_RELAXED,
                                           __HIP_MEMORY_SCOPE_AGENT);
                }
                hTu[2][tid] = (u32)y0;  // benign race: garbage -> unread red2 rows
                hTu[3][tid] = (u32)y1;
            }
            __syncthreads();

            // ============ phase B ============
            if (tid < 32) {             // stream X update + publish
                const float rec0 = red2[0][2 * jp][ub],     gh0 = red2[0][32 + 2 * jp][ub];
                const float rec1 = red2[0][2 * jp + 1][ub], gh1 = red2[0][32 + 2 * jp + 1][ub];
                h0 += stau0 * (sigm(gx0 + gh0) * tanh_f(d0 + rec0) - h0);
                h1 += stau1 * (sigm(gx1 + gh1) * tanh_f(d1 + rec1) - h1);
                const u32 pr = packh(h0, h1);
                hTu[ub][16 * p + jp] = pr;          // own-col LDS shortcut
                __hip_atomic_store(hbuf + pbNew + (size_t)ub * 256 + 16 * p + jp,
                                   ((u64)knew << 32) | (u64)pr,
                                   __ATOMIC_RELAXED, __HIP_MEMORY_SCOPE_AGENT);
            }
            {   // matvec_Y -> red2[1] (X store-acks drain under this)
                f32x4 acc0 = (f32x4){0.f, 0.f, 0.f, 0.f}, acc1 = acc0;
                #pragma unroll
                for (int ks = 0; ks < 16; ks += 2) {
                    const f16x8 a0 = *(const f16x8*)(hrow + ks * 32 + kq);
                    const f16x8 a1 = *(const f16x8*)(hrow + (ks + 1) * 32 + kq);
                    acc0 = __builtin_amdgcn_mfma_f32_16x16x32_f16(a0, Wf[ks],     acc0, 0, 0, 0);
                    acc1 = __builtin_amdgcn_mfma_f32_16x16x32_f16(a1, Wf[ks + 1], acc1, 0, 0, 0);
                }
                #pragma unroll
                for (int r = 0; r < 4; ++r) red2[1][redn][redb + r] = acc0[r] + acc1[r];
            }
            __syncthreads();

            // ============ phase C ============
            u64 x0 = 0, x1 = 0;
            if (!own) {                 // issue gather_X[knew] FIRST (loads
                x0 = __hip_atomic_load(sbN,       __ATOMIC_RELAXED,   // older than
                                       __HIP_MEMORY_SCOPE_AGENT);     // publish_Y
                x1 = __hip_atomic_load(sbN + 256, __ATOMIC_RELAXED,   // stores)
                                       __HIP_MEMORY_SCOPE_AGENT);
            }
            if (tid >= 32 && tid < 64) {  // stream Y update + publish
                const float rec0 = red2[1][2 * jp][ub],     gh0 = red2[1][32 + 2 * jp][ub];
                const float rec1 = red2[1][2 * jp + 1][ub], gh1 = red2[1][32 + 2 * jp + 1][ub];
                h0 += stau0 * (sigm(gx0 + gh0) * tanh_f(d0 + rec0) - h0);
                h1 += stau1 * (sigm(gx1 + gh1) * tanh_f(d1 + rec1) - h1);
                const u32 pr = packh(h0, h1);
                hTu[ub][16 * p + jp] = pr;          // own-col LDS shortcut
                __hip_atomic_store(hbuf + pbNew + (size_t)ub * 256 + 16 * p + jp,
                                   ((u64)knew << 32) | (u64)pr,
                                   __ATOMIC_RELAXED, __HIP_MEMORY_SCOPE_AGENT);
            }
            if (!own) {
                while (!stamp2(x0, x1, knew) && --budget > 0) {
                    x0 = __hip_atomic_load(sbN,       __ATOMIC_RELAXED,
                                           __HIP_MEMORY_SCOPE_AGENT);
                    x1 = __hip_atomic_load(sbN + 256, __ATOMIC_RELAXED,
                                           __HIP_MEMORY_SCOPE_AGENT);
                }
                hTu[0][tid] = (u32)x0;
                hTu[1][tid] = (u32)x1;
            }
            __syncthreads();
            kp1 = knew;
        }
        if (tid < 64) drive[dwofs + (size_t)l * 256] = packh(h0, h1);  // fwd
        dw = dn; gw = gn;
    }
    if (tid < 64) {
        hlast[(size_t)gb * LTC_H + j0]     = h0;
        hlast[(size_t)gb * LTC_H + j0 + 1] = h1;
    }
}

// ---------------------------------------------------------------------------
extern "C" void kernel_launch(void* const* d_in, const int* in_sizes, int n_in,
                              void* d_out, int out_size, void* d_ws, size_t ws_size,
                              hipStream_t stream)
{
    const float* x       = (const float*)d_in[0];
    const float* log_tau = (const float*)d_in[1];
    const float* W_in    = (const float*)d_in[2];
    const float* b_in    = (const float*)d_in[3];
    const float* W_rec   = (const float*)d_in[4];
    const float* W_gate  = (const float*)d_in[5];
    const float* b_gate  = (const float*)d_in[6];
    const float* W_out   = (const float*)d_in[7];
    const float* b_out   = (const float*)d_in[8];

    float* out   = (float*)d_out;                       // (32,1024,512) fp32
    float* hlast = out + (size_t)LTC_B * LTC_L * LTC_H; // (32,512) fp32

    u32* ws    = (u32*)d_ws;                   // 64 MB + 128 KB used
    u32* drive = ws;                           // 8388608 u32 (f16 pairs)
    u32* gatex = ws + 8388608;                 // 8388608 u32
    u64* hbuf  = (u64*)(ws + 16777216);        // 16384 u64 stamped pairs

    const int blocks = (LTC_B * LTC_L / 64) * (LTC_H / 64) / 4;   // 1024

    gemm_a32_c16<<<blocks, 256, 0, stream>>>(x, W_in, LTC_D, b_in, (u16*)drive);
    gemm_a32_c16<<<blocks, 256, 0, stream>>>(x, W_gate, LTC_D + LTC_H, b_gate, (u16*)gatex);
    ltc_scan<<<NG * NP, 256, 0, stream>>>(drive, gatex, W_rec, W_gate, log_tau,
                                          hbuf, hlast);
    gemm_a16_c32<<<blocks, 256, 0, stream>>>((const u16*)drive, W_out, b_out, out);
}

// Round 8
// 10484.576 us; speedup vs baseline: 1.1217x; 1.1217x over previous
//
#include <hip/hip_runtime.h>

typedef unsigned short u16;
typedef unsigned int   u32;
typedef unsigned long long u64;

#define LTC_B 32
#define LTC_L 1024
#define LTC_D 512
#define LTC_H 512
#define NG 8               // groups
#define NP 16              // producer WGs per group (each owns 32+32 W rows)
#define NBG 4              // batches per group

typedef _Float16 f16x8  __attribute__((ext_vector_type(8)));
typedef _Float16 f16x2t __attribute__((ext_vector_type(2)));
typedef float    f32x4  __attribute__((ext_vector_type(4)));
typedef u32      u32x4v __attribute__((ext_vector_type(4)));

static __device__ __forceinline__ u32 packh(float a, float b) {
    f16x2t p; p[0] = (_Float16)a; p[1] = (_Float16)b;
    return __builtin_bit_cast(u32, p);
}
static __device__ __forceinline__ float unplo(u32 w) {
    return (float)__builtin_bit_cast(f16x2t, w)[0];
}
static __device__ __forceinline__ float unphi(u32 w) {
    return (float)__builtin_bit_cast(f16x2t, w)[1];
}
static __device__ __forceinline__ float sigm(float x) {
    return 1.f / (1.f + __expf(-x));
}
static __device__ __forceinline__ float tanh_f(float x) {
    float e = __expf(2.f * x);          // inf-safe: e=inf -> 1, e=0 -> -1
    return 1.f - 2.f / (e + 1.f);
}
static __device__ __forceinline__ f16x8 cvt8(const float* p) {
    const float4 a = *(const float4*)p;
    const float4 b = *(const float4*)(p + 4);
    f16x8 r;
    r[0] = (_Float16)a.x; r[1] = (_Float16)a.y; r[2] = (_Float16)a.z; r[3] = (_Float16)a.w;
    r[4] = (_Float16)b.x; r[5] = (_Float16)b.y; r[6] = (_Float16)b.z; r[7] = (_Float16)b.w;
    return r;
}
// split issue/wait 16B coherent load (agent-scope semantics: sc0 sc1), so the
// LLC RTT can hide under compute between the two calls. Data-dep through r.
static __device__ __forceinline__ u32x4v gld_issue(const u64* p) {
    u32x4v r;
    asm volatile("global_load_dwordx4 %0, %1, off sc0 sc1"
                 : "=v"(r) : "v"((u64)p) : "memory");
    return r;
}
static __device__ __forceinline__ void gld_wait(u32x4v& r) {
    asm volatile("s_waitcnt vmcnt(0)" : "+v"(r) : : "memory");
}

// ---------------------------------------------------------------------------
// C[M,512](f16) = A[M,512](f32) . W[:,:512]^T(f32, row stride ldb) + bias(f32)
// ---------------------------------------------------------------------------
__global__ __launch_bounds__(256) void gemm_a32_c16(
    const float* __restrict__ A, const float* __restrict__ W, int ldb,
    const float* __restrict__ bias, u16* __restrict__ C)
{
    const int wave = threadIdx.x >> 6;
    const int lane = threadIdx.x & 63;
    const int tile = blockIdx.x * 4 + wave;
    const int nt = tile & 7;
    const int mt = tile >> 3;
    const int r16 = lane & 15;
    const int kq  = (lane >> 4) * 8;

    const float* ap = A + (size_t)(mt * 64 + r16) * LTC_D + kq;
    const float* wp = W + (size_t)(nt * 64 + r16) * ldb + kq;

    f32x4 acc[4][4];
    #pragma unroll
    for (int i = 0; i < 4; ++i)
        #pragma unroll
        for (int jj = 0; jj < 4; ++jj) acc[i][jj] = (f32x4){0.f, 0.f, 0.f, 0.f};

    for (int ks = 0; ks < 16; ++ks) {
        f16x8 af[4], bf[4];
        #pragma unroll
        for (int t = 0; t < 4; ++t) {
            af[t] = cvt8(ap + (size_t)t * 16 * LTC_D + ks * 32);
            bf[t] = cvt8(wp + (size_t)t * 16 * ldb  + ks * 32);
        }
        #pragma unroll
        for (int mi = 0; mi < 4; ++mi)
            #pragma unroll
            for (int ni = 0; ni < 4; ++ni)
                acc[mi][ni] = __builtin_amdgcn_mfma_f32_16x16x32_f16(
                    af[mi], bf[ni], acc[mi][ni], 0, 0, 0);
    }
    const int row = (lane >> 4) * 4;   // C/D: col=lane&15 (n), row=(lane>>4)*4+reg (m)
    const int col = lane & 15;
    #pragma unroll
    for (int ni = 0; ni < 4; ++ni) {
        const int n = nt * 64 + ni * 16 + col;
        const float bv = bias[n];
        #pragma unroll
        for (int mi = 0; mi < 4; ++mi)
            #pragma unroll
            for (int r = 0; r < 4; ++r) {
                _Float16 h = (_Float16)(acc[mi][ni][r] + bv);
                C[(size_t)(mt * 64 + mi * 16 + row + r) * LTC_H + n] =
                    __builtin_bit_cast(u16, h);
            }
    }
}

// ---------------------------------------------------------------------------
// C[M,512](f32) = A[M,512](f16) . W^T(f32, row stride 512) + bias(f32)
// ---------------------------------------------------------------------------
__global__ __launch_bounds__(256) void gemm_a16_c32(
    const u16* __restrict__ A, const float* __restrict__ W,
    const float* __restrict__ bias, float* __restrict__ C)
{
    const int wave = threadIdx.x >> 6;
    const int lane = threadIdx.x & 63;
    const int tile = blockIdx.x * 4 + wave;
    const int nt = tile & 7;
    const int mt = tile >> 3;
    const int r16 = lane & 15;
    const int kq  = (lane >> 4) * 8;

    const _Float16* ap = (const _Float16*)A + (size_t)(mt * 64 + r16) * LTC_D + kq;
    const float*    wp = W + (size_t)(nt * 64 + r16) * LTC_H + kq;

    f32x4 acc[4][4];
    #pragma unroll
    for (int i = 0; i < 4; ++i)
        #pragma unroll
        for (int jj = 0; jj < 4; ++jj) acc[i][jj] = (f32x4){0.f, 0.f, 0.f, 0.f};

    for (int ks = 0; ks < 16; ++ks) {
        f16x8 af[4], bf[4];
        #pragma unroll
        for (int t = 0; t < 4; ++t) {
            af[t] = *(const f16x8*)(ap + (size_t)t * 16 * LTC_D + ks * 32);
            bf[t] = cvt8(wp + (size_t)t * 16 * LTC_H + ks * 32);
        }
        #pragma unroll
        for (int mi = 0; mi < 4; ++mi)
            #pragma unroll
            for (int ni = 0; ni < 4; ++ni)
                acc[mi][ni] = __builtin_amdgcn_mfma_f32_16x16x32_f16(
                    af[mi], bf[ni], acc[mi][ni], 0, 0, 0);
    }
    const int row = (lane >> 4) * 4;
    const int col = lane & 15;
    #pragma unroll
    for (int ni = 0; ni < 4; ++ni) {
        const int n = nt * 64 + ni * 16 + col;
        const float bv = bias[n];
        #pragma unroll
        for (int mi = 0; mi < 4; ++mi)
            #pragma unroll
            for (int r = 0; r < 4; ++r)
                C[(size_t)(mt * 64 + mi * 16 + row + r) * LTC_H + n] =
                    acc[mi][ni][r] + bv;
    }
}

// ---------------------------------------------------------------------------
// ODE scan: 8 groups x 4 batches, 16 producer WGs per group (128 WGs).
// EXACT round-6 batch-stream pipeline (verified best, 9.9ms) with two edits:
// (1) FUSED GATHER: each gather thread handles an ADJACENT column pair of
//     ONE stream row (flat 2t,2t+1 of the 2-row block) via a single 16B
//     coherent load (sc0 sc1, = agent-atomic semantics), issued early and
//     waited late — halves LLC sweep transactions (contention on the 16KB
//     hbuf region) with identical bytes/stamp checks/budget. Publisher side
//     byte-identical.
// (2) PHASE-B REORDER: matvec_Y MFMAs issue first; update_X's exp chain
//     runs in the MFMA shadow; red2[1] writes (carrying the MFMA waitcnt)
//     come last — removes wave 0's ~200cyc straggler at the B barrier.
//     matvec_Y's rows 0-1 output is garbage-by-design either way.
// Pipeline phases (all loads issued AND consumed within one barrier
// interval — round-5 lesson: __syncthreads drains vmcnt(0)):
//   phase A: issue gather_Y[k] | matvec_X -> red2[0] | wait+check Y -> hTu 2-3
//   phase B: matvec_Y MFMAs | update_X + publish X[k+1] | red2[1] writes
//   phase C: issue gather_X[k+1] | update_Y + publish Y[k+1] | wait+check X
// Exchange channel = the VALIDATED one: stamped u64 (stamp<<32 | f16 pair),
// agent-scope coherent ops, bounded spin budget (protocol failure => wrong
// answer via absmax, never a hang). Parity safety by the transitive stamp
// argument (publishing t+2 requires all WGs checked t+1, hence finished
// reading t).
// ---------------------------------------------------------------------------
__global__ __launch_bounds__(256) void ltc_scan(
    u32* __restrict__ drive,            // f16 pairs; rewritten with fwd
    const u32* __restrict__ gatex,      // f16 pairs
    const float* __restrict__ W_rec,
    const float* __restrict__ W_gate,
    const float* __restrict__ log_tau,
    u64* __restrict__ hbuf,             // [2 par][8 g][4 b][256] stamped pairs
    float* __restrict__ hlast)
{
    const int g   = blockIdx.x & 7;     // group
    const int p   = blockIdx.x >> 3;    // producer slice 0..15
    const int tid = threadIdx.x;
    const int lane = tid & 63;
    const int wv   = tid >> 6;          // n-tile: 0-1 rec rows, 2-3 gate rows

    __shared__ u32 hTu[16][260];        // h pairs; rows 0-1 = X, 2-3 = Y
    __shared__ float red2[2][64][17];   // [0]=X matvec results, [1]=Y

    // ---- one-time: B-fragments (my 32 W_rec + 32 Wg_h rows) into registers
    const int nl = wv * 16 + (lane & 15);      // 0..63
    const int kq = (lane >> 4) * 8;
    const float* wrow = (nl < 32)
        ? (W_rec  + (size_t)(32 * p + nl) * LTC_H)
        : (W_gate + (size_t)(32 * p + nl - 32) * (LTC_D + LTC_H) + LTC_D);
    f16x8 Wf[16];
    #pragma unroll
    for (int ks = 0; ks < 16; ++ks) Wf[ks] = cvt8(wrow + ks * 32 + kq);

    for (int i = tid; i < 16 * 260; i += 256) (&hTu[0][0])[i] = 0;  // h0 = 0

    // ---- update-thread setup (tid<64: 4 b x 16 pairs; tid<32 = stream X)
    const int ub = tid >> 4;            // local batch (tid<64)
    const int jp = tid & 15;
    const int j0 = 32 * p + 2 * jp;
    const int gb = g * NBG + ub;        // global batch
    float h0 = 0.f, h1 = 0.f, stau0 = 0.f, stau1 = 0.f;
    size_t dwofs = 0;
    if (tid < 64) {
        stau0 = (1.f / 6.f) * __expf(-log_tau[j0]);
        stau1 = (1.f / 6.f) * __expf(-log_tau[j0 + 1]);
        dwofs = (size_t)gb * LTC_L * 256 + 16 * p + jp;
        // prologue: publish initial h=0 with stamp 0 into parity 0
        __hip_atomic_store(hbuf + (size_t)g * (NBG * 256) + (size_t)ub * 256
                               + 16 * p + jp,
                           0ull, __ATOMIC_RELAXED, __HIP_MEMORY_SCOPE_AGENT);
    }
    __syncthreads();

    const _Float16* hrow = (const _Float16*)&hTu[lane & 15][0];
    const int redn = wv * 16 + (lane & 15);
    const int redb = (lane >> 4) * 4;
    u32 kp1 = 0;                        // stamp of current (gathered) state
    int budget = 1 << 22;               // global failing-poll budget (no hangs)

    // fused-gather mapping: thread t handles adjacent col pair (gc0,gc0+1)
    // of stream row grow; skips its own WG's 16-col slice (LDS shortcut).
    const int gh   = tid & 127;
    const int grow = tid >> 7;          // 0 or 1 within the 2-row stream block
    const int gc0  = 2 * gh;
    const bool gskip = (gh >> 3) == p;

    // prime l=0 inputs
    u32 dw = 0, gw = 0;
    if (tid < 64) { dw = drive[dwofs]; gw = gatex[dwofs]; }

    for (int l = 0; l < LTC_L; ++l) {
        const float d0 = unplo(dw), d1 = unphi(dw);
        const float gx0 = unplo(gw), gx1 = unphi(gw);
        // prefetch next step's inputs (drains at next vmcnt(0) under cover)
        u32 dn = 0, gn = 0;
        if (tid < 64 && l + 1 < LTC_L) {
            dn = drive[dwofs + (size_t)(l + 1) * 256];
            gn = gatex[dwofs + (size_t)(l + 1) * 256];
        }
        #pragma unroll 1
        for (int s = 0; s < 6; ++s) {
            const u32 kold = kp1, knew = kp1 + 1;
            const size_t pbOld = (size_t)((kold & 1u) * NG + g) * (NBG * 256);
            const size_t pbNew = (size_t)((knew & 1u) * NG + g) * (NBG * 256);

            // ============ phase A ============
            const u64* gpY = hbuf + pbOld + 512 + (size_t)grow * 256 + gc0;
            u32x4v gy = {0, 0, 0, 0};
            if (!gskip) gy = gld_issue(gpY);    // rows 2-3 pair, stamp kold
            {   // matvec_X -> red2[0] (gather_Y RTT hides under this)
                f32x4 acc0 = (f32x4){0.f, 0.f, 0.f, 0.f}, acc1 = acc0;
                #pragma unroll
                for (int ks = 0; ks < 16; ks += 2) {
                    const f16x8 a0 = *(const f16x8*)(hrow + ks * 32 + kq);
                    const f16x8 a1 = *(const f16x8*)(hrow + (ks + 1) * 32 + kq);
                    acc0 = __builtin_amdgcn_mfma_f32_16x16x32_f16(a0, Wf[ks],     acc0, 0, 0, 0);
                    acc1 = __builtin_amdgcn_mfma_f32_16x16x32_f16(a1, Wf[ks + 1], acc1, 0, 0, 0);
                }
                #pragma unroll
                for (int r = 0; r < 4; ++r) red2[0][redn][redb + r] = acc0[r] + acc1[r];
            }
            if (!gskip) {
                gld_wait(gy);
                while (!((gy[1] == kold) & (gy[3] == kold)) && --budget > 0) {
                    gy = gld_issue(gpY); gld_wait(gy);
                }
                hTu[2 + grow][gc0]     = gy[0];
                hTu[2 + grow][gc0 + 1] = gy[2];
            }
            __syncthreads();

            // ============ phase B ============
            {   // matvec_Y MFMAs first; update_X runs in their shadow
                f32x4 acc0 = (f32x4){0.f, 0.f, 0.f, 0.f}, acc1 = acc0;
                #pragma unroll
                for (int ks = 0; ks < 16; ks += 2) {
                    const f16x8 a0 = *(const f16x8*)(hrow + ks * 32 + kq);
                    const f16x8 a1 = *(const f16x8*)(hrow + (ks + 1) * 32 + kq);
                    acc0 = __builtin_amdgcn_mfma_f32_16x16x32_f16(a0, Wf[ks],     acc0, 0, 0, 0);
                    acc1 = __builtin_amdgcn_mfma_f32_16x16x32_f16(a1, Wf[ks + 1], acc1, 0, 0, 0);
                }
                if (tid < 32) {         // stream X update + publish
                    const float rec0 = red2[0][2 * jp][ub],     gh0 = red2[0][32 + 2 * jp][ub];
                    const float rec1 = red2[0][2 * jp + 1][ub], gh1 = red2[0][32 + 2 * jp + 1][ub];
                    h0 += stau0 * (sigm(gx0 + gh0) * tanh_f(d0 + rec0) - h0);
                    h1 += stau1 * (sigm(gx1 + gh1) * tanh_f(d1 + rec1) - h1);
                    const u32 pr = packh(h0, h1);
                    hTu[ub][16 * p + jp] = pr;          // own-col LDS shortcut
                    __hip_atomic_store(hbuf + pbNew + (size_t)ub * 256 + 16 * p + jp,
                                       ((u64)knew << 32) | (u64)pr,
                                       __ATOMIC_RELAXED, __HIP_MEMORY_SCOPE_AGENT);
                }
                #pragma unroll
                for (int r = 0; r < 4; ++r) red2[1][redn][redb + r] = acc0[r] + acc1[r];
            }
            __syncthreads();

            // ============ phase C ============
            const u64* gpX = hbuf + pbNew + (size_t)grow * 256 + gc0;
            u32x4v gx = {0, 0, 0, 0};
            if (!gskip) gx = gld_issue(gpX);    // rows 0-1 pair, stamp knew
            if (tid >= 32 && tid < 64) {  // stream Y update + publish
                const float rec0 = red2[1][2 * jp][ub],     gh0 = red2[1][32 + 2 * jp][ub];
                const float rec1 = red2[1][2 * jp + 1][ub], gh1 = red2[1][32 + 2 * jp + 1][ub];
                h0 += stau0 * (sigm(gx0 + gh0) * tanh_f(d0 + rec0) - h0);
                h1 += stau1 * (sigm(gx1 + gh1) * tanh_f(d1 + rec1) - h1);
                const u32 pr = packh(h0, h1);
                hTu[ub][16 * p + jp] = pr;          // own-col LDS shortcut
                __hip_atomic_store(hbuf + pbNew + (size_t)ub * 256 + 16 * p + jp,
                                   ((u64)knew << 32) | (u64)pr,
                                   __ATOMIC_RELAXED, __HIP_MEMORY_SCOPE_AGENT);
            }
            if (!gskip) {
                gld_wait(gx);
                while (!((gx[1] == knew) & (gx[3] == knew)) && --budget > 0) {
                    gx = gld_issue(gpX); gld_wait(gx);
                }
                hTu[grow][gc0]     = gx[0];
                hTu[grow][gc0 + 1] = gx[2];
            }
            __syncthreads();
            kp1 = knew;
        }
        if (tid < 64) drive[dwofs + (size_t)l * 256] = packh(h0, h1);  // fwd
        dw = dn; gw = gn;
    }
    if (tid < 64) {
        hlast[(size_t)gb * LTC_H + j0]     = h0;
        hlast[(size_t)gb * LTC_H + j0 + 1] = h1;
    }
}

// ---------------------------------------------------------------------------
extern "C" void kernel_launch(void* const* d_in, const int* in_sizes, int n_in,
                              void* d_out, int out_size, void* d_ws, size_t ws_size,
                              hipStream_t stream)
{
    const float* x       = (const float*)d_in[0];
    const float* log_tau = (const float*)d_in[1];
    const float* W_in    = (const float*)d_in[2];
    const float* b_in    = (const float*)d_in[3];
    const float* W_rec   = (const float*)d_in[4];
    const float* W_gate  = (const float*)d_in[5];
    const float* b_gate  = (const float*)d_in[6];
    const float* W_out   = (const float*)d_in[7];
    const float* b_out   = (const float*)d_in[8];

    float* out   = (float*)d_out;                       // (32,1024,512) fp32
    float* hlast = out + (size_t)LTC_B * LTC_L * LTC_H; // (32,512) fp32

    u32* ws    = (u32*)d_ws;                   // 64 MB + 128 KB used
    u32* drive = ws;                           // 8388608 u32 (f16 pairs)
    u32* gatex = ws + 8388608;                 // 8388608 u32
    u64* hbuf  = (u64*)(ws + 16777216);        // 16384 u64 stamped pairs

    const int blocks = (LTC_B * LTC_L / 64) * (LTC_H / 64) / 4;   // 1024

    gemm_a32_c16<<<blocks, 256, 0, stream>>>(x, W_in, LTC_D, b_in, (u16*)drive);
    gemm_a32_c16<<<blocks, 256, 0, stream>>>(x, W_gate, LTC_D + LTC_H, b_gate, (u16*)gatex);
    ltc_scan<<<NG * NP, 256, 0, stream>>>(drive, gatex, W_rec, W_gate, log_tau,
                                          hbuf, hlast);
    gemm_a16_c32<<<blocks, 256, 0, stream>>>((const u16*)drive, W_out, b_out, out);
}

// Round 9
// 9021.302 us; speedup vs baseline: 1.3036x; 1.1622x over previous
//
#include <hip/hip_runtime.h>

typedef unsigned short u16;
typedef unsigned int   u32;
typedef unsigned long long u64;

#define LTC_B 32
#define LTC_L 1024
#define LTC_D 512
#define LTC_H 512
#define NG 8               // groups
#define NP 16              // producer WGs per group (each owns 32+32 W rows)
#define NBG 4              // batches per group

typedef _Float16 f16x8  __attribute__((ext_vector_type(8)));
typedef _Float16 f16x2t __attribute__((ext_vector_type(2)));
typedef float    f32x4  __attribute__((ext_vector_type(4)));

static __device__ __forceinline__ u32 packh(float a, float b) {
    f16x2t p; p[0] = (_Float16)a; p[1] = (_Float16)b;
    return __builtin_bit_cast(u32, p);
}
static __device__ __forceinline__ float unplo(u32 w) {
    return (float)__builtin_bit_cast(f16x2t, w)[0];
}
static __device__ __forceinline__ float unphi(u32 w) {
    return (float)__builtin_bit_cast(f16x2t, w)[1];
}
static __device__ __forceinline__ float sigm(float x) {
    return 1.f / (1.f + __expf(-x));
}
static __device__ __forceinline__ float tanh_f(float x) {
    float e = __expf(2.f * x);          // inf-safe: e=inf -> 1, e=0 -> -1
    return 1.f - 2.f / (e + 1.f);
}
static __device__ __forceinline__ f16x8 cvt8(const float* p) {
    const float4 a = *(const float4*)p;
    const float4 b = *(const float4*)(p + 4);
    f16x8 r;
    r[0] = (_Float16)a.x; r[1] = (_Float16)a.y; r[2] = (_Float16)a.z; r[3] = (_Float16)a.w;
    r[4] = (_Float16)b.x; r[5] = (_Float16)b.y; r[6] = (_Float16)b.z; r[7] = (_Float16)b.w;
    return r;
}
static __device__ __forceinline__ bool stamp2(u64 a, u64 b, u32 k) {
    return ((u32)(a >> 32) == k) & ((u32)(b >> 32) == k);
}
static __device__ __forceinline__ bool stamp4(u64 a, u64 b, u64 c, u64 d, u32 k) {
    return ((u32)(a >> 32) == k) & ((u32)(b >> 32) == k) &
           ((u32)(c >> 32) == k) & ((u32)(d >> 32) == k);
}

// ---------------------------------------------------------------------------
// C[M,512](f16) = A[M,512](f32) . W[:,:512]^T(f32, row stride ldb) + bias(f32)
// ---------------------------------------------------------------------------
__global__ __launch_bounds__(256) void gemm_a32_c16(
    const float* __restrict__ A, const float* __restrict__ W, int ldb,
    const float* __restrict__ bias, u16* __restrict__ C)
{
    const int wave = threadIdx.x >> 6;
    const int lane = threadIdx.x & 63;
    const int tile = blockIdx.x * 4 + wave;
    const int nt = tile & 7;
    const int mt = tile >> 3;
    const int r16 = lane & 15;
    const int kq  = (lane >> 4) * 8;

    const float* ap = A + (size_t)(mt * 64 + r16) * LTC_D + kq;
    const float* wp = W + (size_t)(nt * 64 + r16) * ldb + kq;

    f32x4 acc[4][4];
    #pragma unroll
    for (int i = 0; i < 4; ++i)
        #pragma unroll
        for (int jj = 0; jj < 4; ++jj) acc[i][jj] = (f32x4){0.f, 0.f, 0.f, 0.f};

    for (int ks = 0; ks < 16; ++ks) {
        f16x8 af[4], bf[4];
        #pragma unroll
        for (int t = 0; t < 4; ++t) {
            af[t] = cvt8(ap + (size_t)t * 16 * LTC_D + ks * 32);
            bf[t] = cvt8(wp + (size_t)t * 16 * ldb  + ks * 32);
        }
        #pragma unroll
        for (int mi = 0; mi < 4; ++mi)
            #pragma unroll
            for (int ni = 0; ni < 4; ++ni)
                acc[mi][ni] = __builtin_amdgcn_mfma_f32_16x16x32_f16(
                    af[mi], bf[ni], acc[mi][ni], 0, 0, 0);
    }
    const int row = (lane >> 4) * 4;   // C/D: col=lane&15 (n), row=(lane>>4)*4+reg (m)
    const int col = lane & 15;
    #pragma unroll
    for (int ni = 0; ni < 4; ++ni) {
        const int n = nt * 64 + ni * 16 + col;
        const float bv = bias[n];
        #pragma unroll
        for (int mi = 0; mi < 4; ++mi)
            #pragma unroll
            for (int r = 0; r < 4; ++r) {
                _Float16 h = (_Float16)(acc[mi][ni][r] + bv);
                C[(size_t)(mt * 64 + mi * 16 + row + r) * LTC_H + n] =
                    __builtin_bit_cast(u16, h);
            }
    }
}

// ---------------------------------------------------------------------------
// C[M,512](f32) = A[M,512](f16) . W^T(f32, row stride 512) + bias(f32)
// ---------------------------------------------------------------------------
__global__ __launch_bounds__(256) void gemm_a16_c32(
    const u16* __restrict__ A, const float* __restrict__ W,
    const float* __restrict__ bias, float* __restrict__ C)
{
    const int wave = threadIdx.x >> 6;
    const int lane = threadIdx.x & 63;
    const int tile = blockIdx.x * 4 + wave;
    const int nt = tile & 7;
    const int mt = tile >> 3;
    const int r16 = lane & 15;
    const int kq  = (lane >> 4) * 8;

    const _Float16* ap = (const _Float16*)A + (size_t)(mt * 64 + r16) * LTC_D + kq;
    const float*    wp = W + (size_t)(nt * 64 + r16) * LTC_H + kq;

    f32x4 acc[4][4];
    #pragma unroll
    for (int i = 0; i < 4; ++i)
        #pragma unroll
        for (int jj = 0; jj < 4; ++jj) acc[i][jj] = (f32x4){0.f, 0.f, 0.f, 0.f};

    for (int ks = 0; ks < 16; ++ks) {
        f16x8 af[4], bf[4];
        #pragma unroll
        for (int t = 0; t < 4; ++t) {
            af[t] = *(const f16x8*)(ap + (size_t)t * 16 * LTC_D + ks * 32);
            bf[t] = cvt8(wp + (size_t)t * 16 * LTC_H + ks * 32);
        }
        #pragma unroll
        for (int mi = 0; mi < 4; ++mi)
            #pragma unroll
            for (int ni = 0; ni < 4; ++ni)
                acc[mi][ni] = __builtin_amdgcn_mfma_f32_16x16x32_f16(
                    af[mi], bf[ni], acc[mi][ni], 0, 0, 0);
    }
    const int row = (lane >> 4) * 4;
    const int col = lane & 15;
    #pragma unroll
    for (int ni = 0; ni < 4; ++ni) {
        const int n = nt * 64 + ni * 16 + col;
        const float bv = bias[n];
        #pragma unroll
        for (int mi = 0; mi < 4; ++mi)
            #pragma unroll
            for (int r = 0; r < 4; ++r)
                C[(size_t)(mt * 64 + mi * 16 + row + r) * LTC_H + n] =
                    acc[mi][ni][r] + bv;
    }
}

// ---------------------------------------------------------------------------
// ODE scan: 8 groups x 4 batches, 16 producer WGs per group (128 WGs of
// 512 threads). WAVE SPECIALIZATION on the round-6 3-phase pipeline
// (verified best): waves 0-3 = matvec ONLY (no global memory ops at all);
// waves 4-5 = updaters (phase B: X, phase C: Y) and phase-A pollers;
// waves 6-7 = phase-C pollers. Each phase is now max(matvec, exchange-leg)
// instead of their sum (round-6's wave 0 ran update AND matvec serially),
// and no thread ever polls in the same phase it published (vmcnt in-order
// retire would stall the poll behind the store ack). Publish is the FIRST
// action of its phase (round-8 lesson: late publish => failed first checks).
//   phase A: matvec_X -> red2[0]  ||  poll Y[kold] -> hTu rows 2-3
//   phase B: matvec_Y -> red2[1]  ||  update_X + publish X[knew] (early)
//   phase C: update_Y + publish Y[knew]  ||  poll X[knew] -> hTu rows 0-1
// Exchange channel = the VALIDATED one, bytes unchanged: stamped u64
// (stamp<<32 | f16 pair), relaxed agent-scope atomics, bounded spin budget
// (protocol failure => wrong answer via absmax, never a hang). Garbage
// confinement: matvec_X rows 2-3 (racing with poll-Y writes) land in
// red2[0] rows never read by update_X (ub 0-1); matvec_Y rows 0-1 (racing
// with update_X own-col writes) land in red2[1] rows never read by
// update_Y (ub 2-3). Overwrite/parity safety by the transitive stamp
// argument (publishing t+2 requires a passed check of all t+1 stamps,
// which implies every WG finished reading t).
// ---------------------------------------------------------------------------
__global__ __launch_bounds__(512) void ltc_scan(
    u32* __restrict__ drive,            // f16 pairs; rewritten with fwd
    const u32* __restrict__ gatex,      // f16 pairs
    const float* __restrict__ W_rec,
    const float* __restrict__ W_gate,
    const float* __restrict__ log_tau,
    u64* __restrict__ hbuf,             // [2 par][8 g][4 b][256] stamped pairs
    float* __restrict__ hlast)
{
    const int g   = blockIdx.x & 7;     // group
    const int p   = blockIdx.x >> 3;    // producer slice 0..15
    const int tid = threadIdx.x;
    const int lane = tid & 63;
    const int wv   = tid >> 6;          // 0-3 matvec, 4-5 update/pollA, 6-7 pollC

    __shared__ u32 hTu[16][260];        // h pairs; rows 0-1 = X, 2-3 = Y
    __shared__ float red2[2][64][17];   // [0]=X matvec results, [1]=Y

    const int kq = (lane >> 4) * 8;

    // ---- matvec waves: B-fragments (32 W_rec + 32 Wg_h rows) in registers
    f16x8 Wf[16];
    if (wv < 4) {
        const int nl = wv * 16 + (lane & 15);      // 0..63
        const float* wrow = (nl < 32)
            ? (W_rec  + (size_t)(32 * p + nl) * LTC_H)
            : (W_gate + (size_t)(32 * p + nl - 32) * (LTC_D + LTC_H) + LTC_D);
        #pragma unroll
        for (int ks = 0; ks < 16; ++ks) Wf[ks] = cvt8(wrow + ks * 32 + kq);
    }

    for (int i = tid; i < 16 * 260; i += 512) (&hTu[0][0])[i] = 0;  // h0 = 0

    // ---- updater setup: tid in [256,320) -> ut 0..63, 4 b x 16 pairs
    const int ut = tid - 256;
    const bool isupd = (ut >= 0) && (ut < 64);
    const int ub = ut >> 4;             // batch 0..3 (X: 0-1, Y: 2-3)
    const int jp = ut & 15;
    const int j0 = 32 * p + 2 * jp;
    const int gb = g * NBG + ub;        // global batch
    float h0 = 0.f, h1 = 0.f, stau0 = 0.f, stau1 = 0.f;
    size_t dwofs = 0;
    if (isupd) {
        stau0 = (1.f / 6.f) * __expf(-log_tau[j0]);
        stau1 = (1.f / 6.f) * __expf(-log_tau[j0 + 1]);
        dwofs = (size_t)gb * LTC_L * 256 + 16 * p + jp;
        // prologue: publish initial h=0 with stamp 0 into parity 0
        __hip_atomic_store(hbuf + (size_t)g * (NBG * 256) + (size_t)ub * 256
                               + 16 * p + jp,
                           0ull, __ATOMIC_RELAXED, __HIP_MEMORY_SCOPE_AGENT);
    }
    __syncthreads();

    const _Float16* hrow = (const _Float16*)&hTu[lane & 15][0];
    const int redn = (wv & 3) * 16 + (lane & 15);
    const int redb = (lane >> 4) * 4;
    u32 kp1 = 0;                        // stamp of current (gathered) state
    int budget = 1 << 22;               // per-thread failing-poll budget

    // phase-A pollers: waves 4-7, col qA, rows 2-3 (2 loads each)
    const int qA = tid - 256;           // 0..255 for waves 4-7
    const bool skipA = ((qA >> 4) == p);
    // phase-C pollers: waves 6-7, cols 2qC,2qC+1, rows 0-1 (4 loads each)
    const int qC = tid - 384;           // 0..127 for waves 6-7
    const bool skipC = ((qC >> 3) == p);   // (2qC)>>4 == qC>>3

    // prime l=0 inputs (updaters only)
    u32 dw = 0, gw = 0;
    if (isupd) { dw = drive[dwofs]; gw = gatex[dwofs]; }

    for (int l = 0; l < LTC_L; ++l) {
        const float d0 = unplo(dw), d1 = unphi(dw);
        const float gx0 = unplo(gw), gx1 = unphi(gw);
        // prefetch next step's inputs (updaters; drains under phase A)
        u32 dn = 0, gn = 0;
        if (isupd && l + 1 < LTC_L) {
            dn = drive[dwofs + (size_t)(l + 1) * 256];
            gn = gatex[dwofs + (size_t)(l + 1) * 256];
        }
        #pragma unroll 1
        for (int s = 0; s < 6; ++s) {
            const u32 kold = kp1, knew = kp1 + 1;
            const size_t pbOld = (size_t)((kold & 1u) * NG + g) * (NBG * 256);
            const size_t pbNew = (size_t)((knew & 1u) * NG + g) * (NBG * 256);

            // ============ phase A ============
            if (wv < 4) {       // matvec_X -> red2[0]
                f32x4 acc0 = (f32x4){0.f, 0.f, 0.f, 0.f}, acc1 = acc0;
                #pragma unroll
                for (int ks = 0; ks < 16; ks += 2) {
                    const f16x8 a0 = *(const f16x8*)(hrow + ks * 32 + kq);
                    const f16x8 a1 = *(const f16x8*)(hrow + (ks + 1) * 32 + kq);
                    acc0 = __builtin_amdgcn_mfma_f32_16x16x32_f16(a0, Wf[ks],     acc0, 0, 0, 0);
                    acc1 = __builtin_amdgcn_mfma_f32_16x16x32_f16(a1, Wf[ks + 1], acc1, 0, 0, 0);
                }
                #pragma unroll
                for (int r = 0; r < 4; ++r) red2[0][redn][redb + r] = acc0[r] + acc1[r];
            } else if (!skipA) {  // poll Y[kold] -> hTu rows 2-3
                const u64* s2 = hbuf + pbOld + 512 + qA;
                const u64* s3 = hbuf + pbOld + 768 + qA;
                u64 a2 = __hip_atomic_load(s2, __ATOMIC_RELAXED,
                                           __HIP_MEMORY_SCOPE_AGENT);
                u64 a3 = __hip_atomic_load(s3, __ATOMIC_RELAXED,
                                           __HIP_MEMORY_SCOPE_AGENT);
                while (!stamp2(a2, a3, kold) && --budget > 0) {
                    a2 = __hip_atomic_load(s2, __ATOMIC_RELAXED,
                                           __HIP_MEMORY_SCOPE_AGENT);
                    a3 = __hip_atomic_load(s3, __ATOMIC_RELAXED,
                                           __HIP_MEMORY_SCOPE_AGENT);
                }
                hTu[2][qA] = (u32)a2;
                hTu[3][qA] = (u32)a3;
            }
            __syncthreads();

            // ============ phase B ============
            if (wv < 4) {       // matvec_Y -> red2[1]
                f32x4 acc0 = (f32x4){0.f, 0.f, 0.f, 0.f}, acc1 = acc0;
                #pragma unroll
                for (int ks = 0; ks < 16; ks += 2) {
                    const f16x8 a0 = *(const f16x8*)(hrow + ks * 32 + kq);
                    const f16x8 a1 = *(const f16x8*)(hrow + (ks + 1) * 32 + kq);
                    acc0 = __builtin_amdgcn_mfma_f32_16x16x32_f16(a0, Wf[ks],     acc0, 0, 0, 0);
                    acc1 = __builtin_amdgcn_mfma_f32_16x16x32_f16(a1, Wf[ks + 1], acc1, 0, 0, 0);
                }
                #pragma unroll
                for (int r = 0; r < 4; ++r) red2[1][redn][redb + r] = acc0[r] + acc1[r];
            } else if (ut < 32) {  // update_X + publish (FIRST action, early)
                const float rec0 = red2[0][2 * jp][ub],     gh0 = red2[0][32 + 2 * jp][ub];
                const float rec1 = red2[0][2 * jp + 1][ub], gh1 = red2[0][32 + 2 * jp + 1][ub];
                h0 += stau0 * (sigm(gx0 + gh0) * tanh_f(d0 + rec0) - h0);
                h1 += stau1 * (sigm(gx1 + gh1) * tanh_f(d1 + rec1) - h1);
                const u32 pr = packh(h0, h1);
                __hip_atomic_store(hbuf + pbNew + (size_t)ub * 256 + 16 * p + jp,
                                   ((u64)knew << 32) | (u64)pr,
                                   __ATOMIC_RELAXED, __HIP_MEMORY_SCOPE_AGENT);
                hTu[ub][16 * p + jp] = pr;          // own-col LDS shortcut
            }
            __syncthreads();

            // ============ phase C ============
            if (ut >= 32 && ut < 64) {  // update_Y + publish (early)
                const float rec0 = red2[1][2 * jp][ub],     gh0 = red2[1][32 + 2 * jp][ub];
                const float rec1 = red2[1][2 * jp + 1][ub], gh1 = red2[1][32 + 2 * jp + 1][ub];
                h0 += stau0 * (sigm(gx0 + gh0) * tanh_f(d0 + rec0) - h0);
                h1 += stau1 * (sigm(gx1 + gh1) * tanh_f(d1 + rec1) - h1);
                const u32 pr = packh(h0, h1);
                __hip_atomic_store(hbuf + pbNew + (size_t)ub * 256 + 16 * p + jp,
                                   ((u64)knew << 32) | (u64)pr,
                                   __ATOMIC_RELAXED, __HIP_MEMORY_SCOPE_AGENT);
                hTu[ub][16 * p + jp] = pr;          // own-col LDS shortcut
            } else if (wv >= 6 && !skipC) {  // poll X[knew] -> hTu rows 0-1
                const int c0 = 2 * qC, c1 = c0 + 1;
                const u64* b0 = hbuf + pbNew;
                u64 a0 = __hip_atomic_load(b0 + c0,       __ATOMIC_RELAXED,
                                           __HIP_MEMORY_SCOPE_AGENT);
                u64 a1 = __hip_atomic_load(b0 + c1,       __ATOMIC_RELAXED,
                                           __HIP_MEMORY_SCOPE_AGENT);
                u64 a2 = __hip_atomic_load(b0 + 256 + c0, __ATOMIC_RELAXED,
                                           __HIP_MEMORY_SCOPE_AGENT);
                u64 a3 = __hip_atomic_load(b0 + 256 + c1, __ATOMIC_RELAXED,
                                           __HIP_MEMORY_SCOPE_AGENT);
                while (!stamp4(a0, a1, a2, a3, knew) && --budget > 0) {
                    a0 = __hip_atomic_load(b0 + c0,       __ATOMIC_RELAXED,
                                           __HIP_MEMORY_SCOPE_AGENT);
                    a1 = __hip_atomic_load(b0 + c1,       __ATOMIC_RELAXED,
                                           __HIP_MEMORY_SCOPE_AGENT);
                    a2 = __hip_atomic_load(b0 + 256 + c0, __ATOMIC_RELAXED,
                                           __HIP_MEMORY_SCOPE_AGENT);
                    a3 = __hip_atomic_load(b0 + 256 + c1, __ATOMIC_RELAXED,
                                           __HIP_MEMORY_SCOPE_AGENT);
                }
                hTu[0][c0] = (u32)a0;
                hTu[0][c1] = (u32)a1;
                hTu[1][c0] = (u32)a2;
                hTu[1][c1] = (u32)a3;
            }
            __syncthreads();
            kp1 = knew;
        }
        if (isupd) drive[dwofs + (size_t)l * 256] = packh(h0, h1);  // fwd
        dw = dn; gw = gn;
    }
    if (isupd) {
        hlast[(size_t)gb * LTC_H + j0]     = h0;
        hlast[(size_t)gb * LTC_H + j0 + 1] = h1;
    }
}

// ---------------------------------------------------------------------------
extern "C" void kernel_launch(void* const* d_in, const int* in_sizes, int n_in,
                              void* d_out, int out_size, void* d_ws, size_t ws_size,
                              hipStream_t stream)
{
    const float* x       = (const float*)d_in[0];
    const float* log_tau = (const float*)d_in[1];
    const float* W_in    = (const float*)d_in[2];
    const float* b_in    = (const float*)d_in[3];
    const float* W_rec   = (const float*)d_in[4];
    const float* W_gate  = (const float*)d_in[5];
    const float* b_gate  = (const float*)d_in[6];
    const float* W_out   = (const float*)d_in[7];
    const float* b_out   = (const float*)d_in[8];

    float* out   = (float*)d_out;                       // (32,1024,512) fp32
    float* hlast = out + (size_t)LTC_B * LTC_L * LTC_H; // (32,512) fp32

    u32* ws    = (u32*)d_ws;                   // 64 MB + 128 KB used
    u32* drive = ws;                           // 8388608 u32 (f16 pairs)
    u32* gatex = ws + 8388608;                 // 8388608 u32
    u64* hbuf  = (u64*)(ws + 16777216);        // 16384 u64 stamped pairs

    const int blocks = (LTC_B * LTC_L / 64) * (LTC_H / 64) / 4;   // 1024

    gemm_a32_c16<<<blocks, 256, 0, stream>>>(x, W_in, LTC_D, b_in, (u16*)drive);
    gemm_a32_c16<<<blocks, 256, 0, stream>>>(x, W_gate, LTC_D + LTC_H, b_gate, (u16*)gatex);
    ltc_scan<<<NG * NP, 512, 0, stream>>>(drive, gatex, W_rec, W_gate, log_tau,
                                          hbuf, hlast);
    gemm_a16_c32<<<blocks, 256, 0, stream>>>((const u16*)drive, W_out, b_out, out);
}